// Round 1
// baseline (661.108 us; speedup 1.0000x reference)
//
#include <hip/hip_runtime.h>
#include <math.h>

#define DIM 300
#define NNODE 127
#define KP 320              // K padded to 10 x 32
#define BK 32
#define ASTR 40             // LDS row stride in shorts (80 B: 16B-aligned)
#define WROW (8*KP)         // shorts per n-row of WT: 8 mats interleaved [n][mat][k]

typedef __attribute__((ext_vector_type(8)))  short bf16x8;
typedef __attribute__((ext_vector_type(16))) float f32x16;

__device__ __forceinline__ unsigned short f2bf(float f){
    unsigned u = __float_as_uint(f);
    u += 0x7fffu + ((u >> 16) & 1u);       // round-to-nearest-even
    return (unsigned short)(u >> 16);
}
__device__ __forceinline__ float sigf(float v){ return 1.0f/(1.0f+__expf(-v)); }
__device__ __forceinline__ float tanh_(float v){
    float t = __expf(-2.0f*fabsf(v));
    float r = (1.0f - t)/(1.0f + t);
    return v < 0.0f ? -r : r;
}

// ---- one-time: transpose + bf16-convert weights into WT[n][mat][k] ----
// mats 0..2: Wioux gates i,o,u ; 3..5: Wiouh ; 6: Wfx ; 7: Wfh. Pad rows/cols with 0.
// Layout [n][mat][k] puts all 8 mats for a given (n,k) within 5120 B so MFMA B-operand
// loads use ONE per-lane address + immediate offsets (mat*640 B).
__global__ void prep_weights(const float* __restrict__ Wioux,
                             const float* __restrict__ Wiouh,
                             const float* __restrict__ Wfx,
                             const float* __restrict__ Wfh,
                             unsigned short* __restrict__ WT)
{
    int k = threadIdx.x;     // 0..319
    int n = blockIdx.x;      // 0..319
    int m = blockIdx.y;      // 0..7
    float v = 0.f;
    if (k < DIM && n < DIM){
        if (m < 3)       v = Wioux[k*(3*DIM) + m*DIM + n];
        else if (m < 6)  v = Wiouh[k*(3*DIM) + (m-3)*DIM + n];
        else if (m == 6) v = Wfx[k*DIM + n];
        else             v = Wfh[k*DIM + n];
    }
    WT[n*WROW + m*KP + k] = f2bf(v);
}

// ---- leaf level (nodes 63..126): iou GEMM only, c = i*u ----
// B operands read directly from WT (L2-resident, 1.6 MB). LDS holds only the A tile (5 KB).
__global__ __launch_bounds__(256,4)
void leaf_mfma(const float* __restrict__ x,
               const float* __restrict__ bioux, const float* __restrict__ biouh,
               const unsigned short* __restrict__ WT,
               float* __restrict__ H, float* __restrict__ C)
{
    __shared__ __attribute__((aligned(16))) short As[64*ASTR];   // 5120 B

    const int t = threadIdx.x;
    const int lane = t & 63, wave = t >> 6;
    const int wm = wave >> 1, wn = wave & 1;
    const int lrow = lane & 31, half = lane >> 5;
    const int rowBase = blockIdx.x * 64;
    const int d0 = blockIdx.y * 64;

    // A staging role: 4 threads per row, 8 floats each
    const int sr = t >> 2, sseg = t & 3;
    const float* xrow;
    {
        int grow = rowBase + sr;
        int b = grow >> 6, j = 63 + (grow & 63);
        xrow = x + (b*NNODE + j)*DIM;
    }
    // per-lane B row base (all 8 mats within 5120 B of this address)
    const unsigned short* wrow = WT + (size_t)(d0 + wn*32 + lrow)*WROW;

    f32x16 accI, accO, accU;
    #pragma unroll
    for (int i = 0; i < 16; i++){ accI[i]=0.f; accO[i]=0.f; accU[i]=0.f; }

    for (int k0 = 0; k0 < KP; k0 += BK){
        // A stage
        {
            int kk0 = k0 + sseg*8;
            bf16x8 px;
            if (kk0 + 8 <= DIM){
                float4 a0 = *(const float4*)(xrow + kk0);
                float4 a1 = *(const float4*)(xrow + kk0 + 4);
                px[0]=f2bf(a0.x); px[1]=f2bf(a0.y); px[2]=f2bf(a0.z); px[3]=f2bf(a0.w);
                px[4]=f2bf(a1.x); px[5]=f2bf(a1.y); px[6]=f2bf(a1.z); px[7]=f2bf(a1.w);
            } else {
                #pragma unroll
                for (int e = 0; e < 8; e++){
                    int k = kk0 + e;
                    px[e] = f2bf(k < DIM ? xrow[k] : 0.f);
                }
            }
            *(bf16x8*)(As + sr*ASTR + sseg*8) = px;
        }
        __syncthreads();
        #pragma unroll
        for (int kk = 0; kk < 2; kk++){
            int ao = (wm*32 + lrow)*ASTR + kk*16 + half*8;
            bf16x8 ax = *(const bf16x8*)(As + ao);
            const unsigned short* wk = wrow + k0 + kk*16 + half*8;
            bf16x8 b0 = *(const bf16x8*)(wk);
            bf16x8 b1 = *(const bf16x8*)(wk + KP);
            bf16x8 b2 = *(const bf16x8*)(wk + 2*KP);
            accI = __builtin_amdgcn_mfma_f32_32x32x16_bf16(ax, b0, accI, 0, 0, 0);
            accO = __builtin_amdgcn_mfma_f32_32x32x16_bf16(ax, b1, accO, 0, 0, 0);
            accU = __builtin_amdgcn_mfma_f32_32x32x16_bf16(ax, b2, accU, 0, 0, 0);
        }
        __syncthreads();
    }
    // epilogue
    int d = d0 + wn*32 + lrow;
    if (d < DIM){
        float bi  = bioux[d]       + biouh[d];
        float bo_ = bioux[DIM+d]   + biouh[DIM+d];
        float bu  = bioux[2*DIM+d] + biouh[2*DIM+d];
        #pragma unroll
        for (int q = 0; q < 16; q++){
            int grow = rowBase + wm*32 + (q&3) + 8*(q>>2) + 4*half;
            int b = grow >> 6, j = 63 + (grow & 63);
            int obase = (b*NNODE + j)*DIM + d;
            float iv = sigf (accI[q] + bi);
            float ov = sigf (accO[q] + bo_);
            float uv = tanh_(accU[q] + bu);
            float cv = iv*uv;
            C[obase] = cv;
            H[obase] = ov*tanh_(cv);
        }
    }
}

// ---- internal levels: 5 fused accumulator groups (Fx folded into F0/F1) ----
// B direct from L2; LDS holds A ops only (x, hsum, h0, h1 = 20 KB).
__global__ __launch_bounds__(256,3)
void level_mfma(const float* __restrict__ x,
                const float* __restrict__ bioux, const float* __restrict__ biouh,
                const float* __restrict__ bfx,   const float* __restrict__ bfh,
                const unsigned short* __restrict__ WT,
                float* __restrict__ H, float* __restrict__ C,
                int lo, int lshift)
{
    __shared__ __attribute__((aligned(16))) short As[4*64*ASTR];  // 20480 B

    const int t = threadIdx.x;
    const int lane = t & 63, wave = t >> 6;
    const int wm = wave >> 1, wn = wave & 1;
    const int lrow = lane & 31, half = lane >> 5;
    const int rowBase = blockIdx.x * 64;
    const int d0 = blockIdx.y * 64;
    const int nmask = (1 << lshift) - 1;

    const int sr = t >> 2, sseg = t & 3;
    const float *xrow, *h0row, *h1row;
    {
        int grow = rowBase + sr;
        int b = grow >> lshift, j = lo + (grow & nmask);
        xrow  = x + (b*NNODE + j)*DIM;
        h0row = H + (b*NNODE + 2*j+1)*DIM;
        h1row = H + (b*NNODE + 2*j+2)*DIM;
    }
    const unsigned short* wrow = WT + (size_t)(d0 + wn*32 + lrow)*WROW;

    f32x16 accI, accO, accU, accF0, accF1;
    #pragma unroll
    for (int i = 0; i < 16; i++){
        accI[i]=0.f; accO[i]=0.f; accU[i]=0.f; accF0[i]=0.f; accF1[i]=0.f;
    }

    #pragma unroll 1
    for (int k0 = 0; k0 < KP; k0 += BK){
        // ---- A stage: x, then h0/h1/hsum ----
        {
            int kk0 = k0 + sseg*8;
            int aoff = sr*ASTR + sseg*8;
            bf16x8 px;
            if (kk0 + 8 <= DIM){
                float4 a0 = *(const float4*)(xrow + kk0);
                float4 a1 = *(const float4*)(xrow + kk0 + 4);
                px[0]=f2bf(a0.x); px[1]=f2bf(a0.y); px[2]=f2bf(a0.z); px[3]=f2bf(a0.w);
                px[4]=f2bf(a1.x); px[5]=f2bf(a1.y); px[6]=f2bf(a1.z); px[7]=f2bf(a1.w);
            } else {
                #pragma unroll
                for (int e = 0; e < 8; e++){
                    int k = kk0 + e;
                    px[e] = f2bf(k < DIM ? xrow[k] : 0.f);
                }
            }
            *(bf16x8*)(As + aoff) = px;

            float h0v[8], h1v[8];
            if (kk0 + 8 <= DIM){
                float4 b0 = *(const float4*)(h0row + kk0);
                float4 b1 = *(const float4*)(h0row + kk0 + 4);
                float4 c0 = *(const float4*)(h1row + kk0);
                float4 c1 = *(const float4*)(h1row + kk0 + 4);
                h0v[0]=b0.x; h0v[1]=b0.y; h0v[2]=b0.z; h0v[3]=b0.w;
                h0v[4]=b1.x; h0v[5]=b1.y; h0v[6]=b1.z; h0v[7]=b1.w;
                h1v[0]=c0.x; h1v[1]=c0.y; h1v[2]=c0.z; h1v[3]=c0.w;
                h1v[4]=c1.x; h1v[5]=c1.y; h1v[6]=c1.z; h1v[7]=c1.w;
            } else {
                #pragma unroll
                for (int e = 0; e < 8; e++){
                    int k = kk0 + e;
                    bool ok = k < DIM;
                    h0v[e] = ok ? h0row[k] : 0.f;
                    h1v[e] = ok ? h1row[k] : 0.f;
                }
            }
            bf16x8 ph, p0, p1;
            #pragma unroll
            for (int e = 0; e < 8; e++){
                p0[e] = f2bf(h0v[e]);
                p1[e] = f2bf(h1v[e]);
                ph[e] = f2bf(h0v[e] + h1v[e]);
            }
            *(bf16x8*)(As + 1*64*ASTR + aoff) = ph;
            *(bf16x8*)(As + 2*64*ASTR + aoff) = p0;
            *(bf16x8*)(As + 3*64*ASTR + aoff) = p1;
        }
        __syncthreads();
        // ---- MFMA: 10 per kk per wave; B straight from L2 ----
        #pragma unroll
        for (int kk = 0; kk < 2; kk++){
            int ao = (wm*32 + lrow)*ASTR + kk*16 + half*8;
            const unsigned short* wk = wrow + k0 + kk*16 + half*8;
            bf16x8 ax = *(const bf16x8*)(As + ao);
            bf16x8 b0 = *(const bf16x8*)(wk);
            bf16x8 b1 = *(const bf16x8*)(wk + KP);
            bf16x8 b2 = *(const bf16x8*)(wk + 2*KP);
            bf16x8 b6 = *(const bf16x8*)(wk + 6*KP);
            accI  = __builtin_amdgcn_mfma_f32_32x32x16_bf16(ax, b0, accI , 0, 0, 0);
            accO  = __builtin_amdgcn_mfma_f32_32x32x16_bf16(ax, b1, accO , 0, 0, 0);
            accU  = __builtin_amdgcn_mfma_f32_32x32x16_bf16(ax, b2, accU , 0, 0, 0);
            accF0 = __builtin_amdgcn_mfma_f32_32x32x16_bf16(ax, b6, accF0, 0, 0, 0);
            accF1 = __builtin_amdgcn_mfma_f32_32x32x16_bf16(ax, b6, accF1, 0, 0, 0);
            bf16x8 ah = *(const bf16x8*)(As + 1*64*ASTR + ao);
            bf16x8 b3 = *(const bf16x8*)(wk + 3*KP);
            bf16x8 b4 = *(const bf16x8*)(wk + 4*KP);
            bf16x8 b5 = *(const bf16x8*)(wk + 5*KP);
            accI  = __builtin_amdgcn_mfma_f32_32x32x16_bf16(ah, b3, accI , 0, 0, 0);
            accO  = __builtin_amdgcn_mfma_f32_32x32x16_bf16(ah, b4, accO , 0, 0, 0);
            accU  = __builtin_amdgcn_mfma_f32_32x32x16_bf16(ah, b5, accU , 0, 0, 0);
            bf16x8 a0 = *(const bf16x8*)(As + 2*64*ASTR + ao);
            bf16x8 a1 = *(const bf16x8*)(As + 3*64*ASTR + ao);
            bf16x8 b7 = *(const bf16x8*)(wk + 7*KP);
            accF0 = __builtin_amdgcn_mfma_f32_32x32x16_bf16(a0, b7, accF0, 0, 0, 0);
            accF1 = __builtin_amdgcn_mfma_f32_32x32x16_bf16(a1, b7, accF1, 0, 0, 0);
        }
        __syncthreads();
    }
    // ---- epilogue ----
    int d = d0 + wn*32 + lrow;
    if (d < DIM){
        float bi  = bioux[d]       + biouh[d];
        float bo_ = bioux[DIM+d]   + biouh[DIM+d];
        float bu  = bioux[2*DIM+d] + biouh[2*DIM+d];
        float bf_ = bfx[d] + bfh[d];
        #pragma unroll
        for (int q = 0; q < 16; q++){
            int grow = rowBase + wm*32 + (q&3) + 8*(q>>2) + 4*half;
            int b = grow >> lshift, j = lo + (grow & nmask);
            int obase = (b*NNODE + j)*DIM + d;
            int c0i = (b*NNODE + 2*j+1)*DIM + d;
            int c1i = (b*NNODE + 2*j+2)*DIM + d;
            float iv = sigf (accI[q] + bi);
            float ov = sigf (accO[q] + bo_);
            float uv = tanh_(accU[q] + bu);
            float f0 = sigf (accF0[q] + bf_);
            float f1 = sigf (accF1[q] + bf_);
            float cv = iv*uv + f0*C[c0i] + f1*C[c1i];
            C[obase] = cv;
            H[obase] = ov*tanh_(cv);
        }
    }
}

extern "C" void kernel_launch(void* const* d_in, const int* in_sizes, int n_in,
                              void* d_out, int out_size, void* d_ws, size_t ws_size,
                              hipStream_t stream) {
    const float* x     = (const float*)d_in[0];
    const float* Wioux = (const float*)d_in[1];
    const float* bioux = (const float*)d_in[2];
    const float* Wiouh = (const float*)d_in[3];
    const float* biouh = (const float*)d_in[4];
    const float* Wfx   = (const float*)d_in[5];
    const float* bfx   = (const float*)d_in[6];
    const float* Wfh   = (const float*)d_in[7];
    const float* bfh   = (const float*)d_in[8];
    float* H = (float*)d_out;
    float* C = (float*)d_ws;                                   // 78,028,800 B
    unsigned short* WT = (unsigned short*)((char*)d_ws + 78028800);  // 1,638,400 B

    prep_weights<<<dim3(KP, 8), KP, 0, stream>>>(Wioux, Wiouh, Wfx, Wfh, WT);
    // leaves: 64 nodes -> 32768 rows
    leaf_mfma<<<dim3(512, 5), 256, 0, stream>>>(x, bioux, biouh, WT, H, C);
    // internal levels deepest-first
    for (int l = 5; l >= 0; l--){
        level_mfma<<<dim3(8 << l, 5), 256, 0, stream>>>(
            x, bioux, biouh, bfx, bfh, WT, H, C, (1 << l) - 1, l);
    }
}

// Round 2
// 539.111 us; speedup vs baseline: 1.2263x; 1.2263x over previous
//
#include <hip/hip_runtime.h>
#include <math.h>

#define DIM 300
#define NNODE 127
#define KP 320              // K padded to 10 x 32
#define BK 32
#define ASTR 40             // LDS row stride in shorts (80 B: 16B-aligned)
#define MATSZ (KP*KP)       // elements per transposed weight matrix

typedef __attribute__((ext_vector_type(8)))  short bf16x8;
typedef __attribute__((ext_vector_type(16))) float f32x16;

// Raw barrier: waits LDS ops only. Deliberately NO vmcnt — prefetch global loads
// stay in flight across the barrier (T14). "memory" clobber pins LDS op ordering.
#define BARRIER() asm volatile("s_waitcnt lgkmcnt(0)\n\ts_barrier" ::: "memory")

__device__ __forceinline__ unsigned short f2bf(float f){
    unsigned u = __float_as_uint(f);
    u += 0x7fffu + ((u >> 16) & 1u);       // round-to-nearest-even
    return (unsigned short)(u >> 16);
}
__device__ __forceinline__ float sigf(float v){ return 1.0f/(1.0f+__expf(-v)); }
__device__ __forceinline__ float tanh_(float v){
    float t = __expf(-2.0f*fabsf(v));
    float r = (1.0f - t)/(1.0f + t);
    return v < 0.0f ? -r : r;
}

// ---- one-time: transpose + bf16-convert weights into WT[8][320][320] ([m][n][k]) ----
// mats 0..2: Wioux gates i,o,u ; 3..5: Wiouh ; 6: Wfx ; 7: Wfh. Pad rows/cols with 0.
__global__ void prep_weights(const float* __restrict__ Wioux,
                             const float* __restrict__ Wiouh,
                             const float* __restrict__ Wfx,
                             const float* __restrict__ Wfh,
                             unsigned short* __restrict__ WT)
{
    int k = threadIdx.x;     // 0..319
    int n = blockIdx.x;      // 0..319
    int m = blockIdx.y;      // 0..7
    float v = 0.f;
    if (k < DIM && n < DIM){
        if (m < 3)       v = Wioux[k*(3*DIM) + m*DIM + n];
        else if (m < 6)  v = Wiouh[k*(3*DIM) + (m-3)*DIM + n];
        else if (m == 6) v = Wfx[k*DIM + n];
        else             v = Wfh[k*DIM + n];
    }
    WT[m*MATSZ + n*KP + k] = f2bf(v);
}

// ---- leaf level (nodes 63..126): iou GEMM only, c = i*u ----
// Pipelined: global loads for k-step t+1 issued under the MFMA phase of step t.
__global__ __launch_bounds__(256,3)
void leaf_mfma(const float* __restrict__ x,
               const float* __restrict__ bioux, const float* __restrict__ biouh,
               const unsigned short* __restrict__ WT,
               float* __restrict__ H, float* __restrict__ C)
{
    __shared__ __attribute__((aligned(16))) short lds[(1+3)*64*ASTR];   // 20480 B
    short* As = lds;                 // x tile: 64 rows x 32 k
    short* Bs = lds + 64*ASTR;       // 3 mats x 64 n x 32 k

    const int t = threadIdx.x;
    const int lane = t & 63, wave = t >> 6;
    const int wm = wave >> 1, wn = wave & 1;
    const int lrow = lane & 31, half = lane >> 5;
    const int rowBase = blockIdx.x * 64;
    const int d0 = blockIdx.y * 64;

    // A staging role: 4 threads per row, 8 floats each
    const int sr = t >> 2, sseg = t & 3;
    const float* xrow;
    {
        int grow = rowBase + sr;
        int b = grow >> 6, j = 63 + (grow & 63);
        xrow = x + (b*NNODE + j)*DIM;
    }
    // B staging role: mats 0..2 on threads 0..95
    const int bm = t >> 5, bn = t & 31;

    f32x16 accI, accO, accU;
    #pragma unroll
    for (int i = 0; i < 16; i++){ accI[i]=0.f; accO[i]=0.f; accU[i]=0.f; }

    float xa[8];
    bf16x8 wstage[2][4];

    auto LOAD = [&](int k0){
        int kk0 = k0 + sseg*8;
        if (kk0 + 8 <= DIM){
            float4 a0 = *(const float4*)(xrow + kk0);
            float4 a1 = *(const float4*)(xrow + kk0 + 4);
            xa[0]=a0.x; xa[1]=a0.y; xa[2]=a0.z; xa[3]=a0.w;
            xa[4]=a1.x; xa[5]=a1.y; xa[6]=a1.z; xa[7]=a1.w;
        } else {
            #pragma unroll
            for (int e = 0; e < 8; e++){
                int k = kk0 + e;
                xa[e] = (k < DIM) ? xrow[k] : 0.f;
            }
        }
        if (bm < 3){
            const unsigned short* wb = WT + bm*MATSZ + k0;
            #pragma unroll
            for (int h2 = 0; h2 < 2; h2++){
                const unsigned short* src = wb + (size_t)(d0 + bn + 32*h2)*KP;
                wstage[h2][0] = *(const bf16x8*)(src);
                wstage[h2][1] = *(const bf16x8*)(src + 8);
                wstage[h2][2] = *(const bf16x8*)(src + 16);
                wstage[h2][3] = *(const bf16x8*)(src + 24);
            }
        }
    };
    auto STORE = [&](){
        bf16x8 px;
        #pragma unroll
        for (int e = 0; e < 8; e++) px[e] = f2bf(xa[e]);
        *(bf16x8*)(As + sr*ASTR + sseg*8) = px;
        if (bm < 3){
            #pragma unroll
            for (int h2 = 0; h2 < 2; h2++){
                short* dst = Bs + bm*64*ASTR + (bn + 32*h2)*ASTR;
                *(bf16x8*)(dst)      = wstage[h2][0];
                *(bf16x8*)(dst + 8)  = wstage[h2][1];
                *(bf16x8*)(dst + 16) = wstage[h2][2];
                *(bf16x8*)(dst + 24) = wstage[h2][3];
            }
        }
    };

    LOAD(0);
    #pragma unroll 1
    for (int ks = 0; ks < KP/BK; ks++){
        STORE();                       // implicit vmcnt wait on staged regs
        BARRIER();                     // writes visible; vmem prefetch unaffected
        if (ks + 1 < KP/BK) LOAD((ks+1)*BK);   // flies under MFMA phase
        #pragma unroll
        for (int kk = 0; kk < 2; kk++){
            int ao = (wm*32 + lrow)*ASTR + kk*16 + half*8;
            bf16x8 ax = *(const bf16x8*)(As + ao);
            int bo = (wn*32 + lrow)*ASTR + kk*16 + half*8;
            bf16x8 b0 = *(const bf16x8*)(Bs + 0*64*ASTR + bo);
            bf16x8 b1 = *(const bf16x8*)(Bs + 1*64*ASTR + bo);
            bf16x8 b2 = *(const bf16x8*)(Bs + 2*64*ASTR + bo);
            accI = __builtin_amdgcn_mfma_f32_32x32x16_bf16(ax, b0, accI, 0, 0, 0);
            accO = __builtin_amdgcn_mfma_f32_32x32x16_bf16(ax, b1, accO, 0, 0, 0);
            accU = __builtin_amdgcn_mfma_f32_32x32x16_bf16(ax, b2, accU, 0, 0, 0);
        }
        BARRIER();                     // reads done before next iter's writes
    }
    // epilogue
    int d = d0 + wn*32 + lrow;
    if (d < DIM){
        float bi  = bioux[d]       + biouh[d];
        float bo_ = bioux[DIM+d]   + biouh[DIM+d];
        float bu  = bioux[2*DIM+d] + biouh[2*DIM+d];
        #pragma unroll
        for (int q = 0; q < 16; q++){
            int grow = rowBase + wm*32 + (q&3) + 8*(q>>2) + 4*half;
            int b = grow >> 6, j = 63 + (grow & 63);
            int obase = (b*NNODE + j)*DIM + d;
            float iv = sigf (accI[q] + bi);
            float ov = sigf (accO[q] + bo_);
            float uv = tanh_(accU[q] + bu);
            float cv = iv*uv;
            C[obase] = cv;
            H[obase] = ov*tanh_(cv);
        }
    }
}

// ---- internal levels: 6 fused accumulator groups, pipelined staging ----
__global__ __launch_bounds__(256,2)
void level_mfma(const float* __restrict__ x,
                const float* __restrict__ bioux, const float* __restrict__ biouh,
                const float* __restrict__ bfx,   const float* __restrict__ bfh,
                const unsigned short* __restrict__ WT,
                float* __restrict__ H, float* __restrict__ C,
                int lo, int lshift)
{
    __shared__ __attribute__((aligned(16))) short lds[(4+8)*64*ASTR];  // 61440 B
    short* As = lds;                  // ops: 0=x 1=hsum 2=h0 3=h1
    short* Bs = lds + 4*64*ASTR;      // 8 mats x 64 n x 32 k

    const int t = threadIdx.x;
    const int lane = t & 63, wave = t >> 6;
    const int wm = wave >> 1, wn = wave & 1;
    const int lrow = lane & 31, half = lane >> 5;
    const int rowBase = blockIdx.x * 64;
    const int d0 = blockIdx.y * 64;
    const int nmask = (1 << lshift) - 1;

    const int sr = t >> 2, sseg = t & 3;
    const float *xrow, *h0row, *h1row;
    {
        int grow = rowBase + sr;
        int b = grow >> lshift, j = lo + (grow & nmask);
        xrow  = x + (b*NNODE + j)*DIM;
        h0row = H + (b*NNODE + 2*j+1)*DIM;
        h1row = H + (b*NNODE + 2*j+2)*DIM;
    }
    const int bm = t >> 5, bn = t & 31;

    f32x16 accI, accO, accU, accFx, accF0, accF1;
    #pragma unroll
    for (int i = 0; i < 16; i++){
        accI[i]=0.f; accO[i]=0.f; accU[i]=0.f;
        accFx[i]=0.f; accF0[i]=0.f; accF1[i]=0.f;
    }

    float xa[8], h0v[8], h1v[8];
    bf16x8 wstage[2][4];

    auto LOAD = [&](int k0){
        int kk0 = k0 + sseg*8;
        if (kk0 + 8 <= DIM){
            float4 a0 = *(const float4*)(xrow + kk0);
            float4 a1 = *(const float4*)(xrow + kk0 + 4);
            float4 b0 = *(const float4*)(h0row + kk0);
            float4 b1 = *(const float4*)(h0row + kk0 + 4);
            float4 c0 = *(const float4*)(h1row + kk0);
            float4 c1 = *(const float4*)(h1row + kk0 + 4);
            xa[0]=a0.x;  xa[1]=a0.y;  xa[2]=a0.z;  xa[3]=a0.w;
            xa[4]=a1.x;  xa[5]=a1.y;  xa[6]=a1.z;  xa[7]=a1.w;
            h0v[0]=b0.x; h0v[1]=b0.y; h0v[2]=b0.z; h0v[3]=b0.w;
            h0v[4]=b1.x; h0v[5]=b1.y; h0v[6]=b1.z; h0v[7]=b1.w;
            h1v[0]=c0.x; h1v[1]=c0.y; h1v[2]=c0.z; h1v[3]=c0.w;
            h1v[4]=c1.x; h1v[5]=c1.y; h1v[6]=c1.z; h1v[7]=c1.w;
        } else {
            #pragma unroll
            for (int e = 0; e < 8; e++){
                int k = kk0 + e;
                bool ok = k < DIM;
                xa[e]  = ok ? xrow[k]  : 0.f;
                h0v[e] = ok ? h0row[k] : 0.f;
                h1v[e] = ok ? h1row[k] : 0.f;
            }
        }
        const unsigned short* wb = WT + bm*MATSZ + k0;
        #pragma unroll
        for (int h2 = 0; h2 < 2; h2++){
            const unsigned short* src = wb + (size_t)(d0 + bn + 32*h2)*KP;
            wstage[h2][0] = *(const bf16x8*)(src);
            wstage[h2][1] = *(const bf16x8*)(src + 8);
            wstage[h2][2] = *(const bf16x8*)(src + 16);
            wstage[h2][3] = *(const bf16x8*)(src + 24);
        }
    };
    auto STORE = [&](){
        int aoff = sr*ASTR + sseg*8;
        bf16x8 px, ph, p0, p1;
        #pragma unroll
        for (int e = 0; e < 8; e++){
            px[e] = f2bf(xa[e]);
            p0[e] = f2bf(h0v[e]);
            p1[e] = f2bf(h1v[e]);
            ph[e] = f2bf(h0v[e] + h1v[e]);
        }
        *(bf16x8*)(As + aoff) = px;
        *(bf16x8*)(As + 1*64*ASTR + aoff) = ph;
        *(bf16x8*)(As + 2*64*ASTR + aoff) = p0;
        *(bf16x8*)(As + 3*64*ASTR + aoff) = p1;
        #pragma unroll
        for (int h2 = 0; h2 < 2; h2++){
            short* dst = Bs + bm*64*ASTR + (bn + 32*h2)*ASTR;
            *(bf16x8*)(dst)      = wstage[h2][0];
            *(bf16x8*)(dst + 8)  = wstage[h2][1];
            *(bf16x8*)(dst + 16) = wstage[h2][2];
            *(bf16x8*)(dst + 24) = wstage[h2][3];
        }
    };

    LOAD(0);
    #pragma unroll 1
    for (int ks = 0; ks < KP/BK; ks++){
        STORE();                       // implicit vmcnt wait on staged regs
        BARRIER();                     // writes visible; vmem prefetch unaffected
        if (ks + 1 < KP/BK) LOAD((ks+1)*BK);   // flies under MFMA phase
        #pragma unroll
        for (int kk = 0; kk < 2; kk++){
            int ao = (wm*32 + lrow)*ASTR + kk*16 + half*8;
            bf16x8 ax = *(const bf16x8*)(As + 0*64*ASTR + ao);
            bf16x8 ah = *(const bf16x8*)(As + 1*64*ASTR + ao);
            bf16x8 a0 = *(const bf16x8*)(As + 2*64*ASTR + ao);
            bf16x8 a1 = *(const bf16x8*)(As + 3*64*ASTR + ao);
            int bo = (wn*32 + lrow)*ASTR + kk*16 + half*8;
            bf16x8 b0 = *(const bf16x8*)(Bs + 0*64*ASTR + bo);
            bf16x8 b1 = *(const bf16x8*)(Bs + 1*64*ASTR + bo);
            bf16x8 b2 = *(const bf16x8*)(Bs + 2*64*ASTR + bo);
            bf16x8 b3 = *(const bf16x8*)(Bs + 3*64*ASTR + bo);
            bf16x8 b4 = *(const bf16x8*)(Bs + 4*64*ASTR + bo);
            bf16x8 b5 = *(const bf16x8*)(Bs + 5*64*ASTR + bo);
            bf16x8 b6 = *(const bf16x8*)(Bs + 6*64*ASTR + bo);
            bf16x8 b7 = *(const bf16x8*)(Bs + 7*64*ASTR + bo);
            accI  = __builtin_amdgcn_mfma_f32_32x32x16_bf16(ax, b0, accI , 0, 0, 0);
            accI  = __builtin_amdgcn_mfma_f32_32x32x16_bf16(ah, b3, accI , 0, 0, 0);
            accO  = __builtin_amdgcn_mfma_f32_32x32x16_bf16(ax, b1, accO , 0, 0, 0);
            accO  = __builtin_amdgcn_mfma_f32_32x32x16_bf16(ah, b4, accO , 0, 0, 0);
            accU  = __builtin_amdgcn_mfma_f32_32x32x16_bf16(ax, b2, accU , 0, 0, 0);
            accU  = __builtin_amdgcn_mfma_f32_32x32x16_bf16(ah, b5, accU , 0, 0, 0);
            accFx = __builtin_amdgcn_mfma_f32_32x32x16_bf16(ax, b6, accFx, 0, 0, 0);
            accF0 = __builtin_amdgcn_mfma_f32_32x32x16_bf16(a0, b7, accF0, 0, 0, 0);
            accF1 = __builtin_amdgcn_mfma_f32_32x32x16_bf16(a1, b7, accF1, 0, 0, 0);
        }
        BARRIER();                     // reads done before next iter's writes
    }
    // ---- epilogue ----
    int d = d0 + wn*32 + lrow;
    if (d < DIM){
        float bi  = bioux[d]       + biouh[d];
        float bo_ = bioux[DIM+d]   + biouh[DIM+d];
        float bu  = bioux[2*DIM+d] + biouh[2*DIM+d];
        float bf_ = bfx[d] + bfh[d];
        #pragma unroll
        for (int q = 0; q < 16; q++){
            int grow = rowBase + wm*32 + (q&3) + 8*(q>>2) + 4*half;
            int b = grow >> lshift, j = lo + (grow & nmask);
            int obase = (b*NNODE + j)*DIM + d;
            int c0i = (b*NNODE + 2*j+1)*DIM + d;
            int c1i = (b*NNODE + 2*j+2)*DIM + d;
            float iv = sigf (accI[q] + bi);
            float ov = sigf (accO[q] + bo_);
            float uv = tanh_(accU[q] + bu);
            float f0 = sigf (accFx[q] + accF0[q] + bf_);
            float f1 = sigf (accFx[q] + accF1[q] + bf_);
            float cv = iv*uv + f0*C[c0i] + f1*C[c1i];
            C[obase] = cv;
            H[obase] = ov*tanh_(cv);
        }
    }
}

extern "C" void kernel_launch(void* const* d_in, const int* in_sizes, int n_in,
                              void* d_out, int out_size, void* d_ws, size_t ws_size,
                              hipStream_t stream) {
    const float* x     = (const float*)d_in[0];
    const float* Wioux = (const float*)d_in[1];
    const float* bioux = (const float*)d_in[2];
    const float* Wiouh = (const float*)d_in[3];
    const float* biouh = (const float*)d_in[4];
    const float* Wfx   = (const float*)d_in[5];
    const float* bfx   = (const float*)d_in[6];
    const float* Wfh   = (const float*)d_in[7];
    const float* bfh   = (const float*)d_in[8];
    float* H = (float*)d_out;
    float* C = (float*)d_ws;                                   // 78,028,800 B
    unsigned short* WT = (unsigned short*)((char*)d_ws + 78028800);  // 1,638,400 B

    prep_weights<<<dim3(KP, 8), KP, 0, stream>>>(Wioux, Wiouh, Wfx, Wfh, WT);
    // leaves: 64 nodes -> 32768 rows
    leaf_mfma<<<dim3(512, 5), 256, 0, stream>>>(x, bioux, biouh, WT, H, C);
    // internal levels deepest-first
    for (int l = 5; l >= 0; l--){
        level_mfma<<<dim3(8 << l, 5), 256, 0, stream>>>(
            x, bioux, biouh, bfx, bfh, WT, H, C, (1 << l) - 1, l);
    }
}